// Round 2
// baseline (247.536 us; speedup 1.0000x reference)
//
#include <hip/hip_runtime.h>
#include <math.h>

#define CCH 512
#define NH 4
#define HD 128
#define HW 1024
#define BATCH 16
#define EPS 1e-5f

typedef __attribute__((ext_vector_type(8))) short bfrag;    // 8 bf16 = 4 VGPRs
typedef __attribute__((ext_vector_type(4))) float f4;
typedef __attribute__((ext_vector_type(16))) float f16v;    // 32x32 accum

static __device__ __forceinline__ unsigned short f2bf(float f) {
  union { float f; unsigned u; } v;
  v.f = f;
  unsigned r = v.u + 0x7fff + ((v.u >> 16) & 1);  // RNE
  return (unsigned short)(r >> 16);
}
static __device__ __forceinline__ unsigned pack2(unsigned short a, unsigned short b) {
  return (unsigned)a | ((unsigned)b << 16);
}
// packed f32x2 -> bf16x2 in one VALU op (gfx950). src0 -> low half.
static __device__ __forceinline__ unsigned cvt_pk_bf16(float a, float b) {
  unsigned r;
  asm("v_cvt_pk_bf16_f32 %0, %1, %2" : "=v"(r) : "v"(a), "v"(b));
  return r;
}
// exp2 via HW transcendental (no log2e multiply; folded into Q scale)
#if defined(__has_builtin) && __has_builtin(__builtin_amdgcn_exp2f)
#define EXP2(x) __builtin_amdgcn_exp2f(x)
#else
#define EXP2(x) __expf((x) * 0.6931471805599453f)  // e^(x ln2) == 2^x
#endif
// async global->LDS, 16B/lane. LDS dest = wave-uniform base + lane*16.
static __device__ __forceinline__ void ldg_lds16(const unsigned short* g,
                                                 unsigned short* l) {
  __builtin_amdgcn_global_load_lds(
      (const __attribute__((address_space(1))) unsigned int*)g,
      (__attribute__((address_space(3))) unsigned int*)l, 16, 0, 0);
}

// softmax scale folded into Q GEMM epilogue. Includes log2(e) so the
// attention softmax can use raw v_exp_f32 (2^x): 2^(s*log2e) == e^s exactly.
#define QSCALE (0.08838834764831845f * 1.4426950408889634f)

// ---------- weights fp32 -> bf16 (4 matrices stacked) ----------
__global__ __launch_bounds__(256) void wcvt_kernel(const float* __restrict__ s0,
                                                   const float* __restrict__ s1,
                                                   const float* __restrict__ s2,
                                                   const float* __restrict__ s3,
                                                   unsigned short* __restrict__ d) {
  const float* srcs[4] = {s0, s1, s2, s3};
  const float* s = srcs[blockIdx.y];
  unsigned short* dp = d + (size_t)blockIdx.y * CCH * CCH;
  int i = blockIdx.x * 256 + threadIdx.x;
  f4 v = ((const f4*)s)[i];
  ushort4 o;
  o.x = f2bf(v.x); o.y = f2bf(v.y); o.z = f2bf(v.z); o.w = f2bf(v.w);
  ((ushort4*)dp)[i] = o;
}

// ---------- GroupNorm -> position-major bf16 hn_t[b][hw][c] ----------
// Single global read: thread t holds channels 0..15 at positions 4t..4t+3 in
// registers (64 floats); stats via shuffle; write directly from registers.
__global__ __launch_bounds__(256) void gn_kernel(const float* __restrict__ x,
                                                 const float* __restrict__ gamma,
                                                 const float* __restrict__ beta,
                                                 unsigned short* __restrict__ hn) {
  int b = blockIdx.x >> 5, g = blockIdx.x & 31;
  const float* xp = x + ((size_t)b * CCH + g * 16) * HW;
  int t = threadIdx.x;
  float s = 0.f, ss = 0.f;
  const f4* xp4 = (const f4*)xp;
  f4 vv[16];
#pragma unroll
  for (int c = 0; c < 16; ++c) {
    f4 v = xp4[c * 256 + t];  // channel c, positions 4t..4t+3
    vv[c] = v;
    s += v.x + v.y + v.z + v.w;
    ss += v.x * v.x + v.y * v.y + v.z * v.z + v.w * v.w;
  }
#pragma unroll
  for (int off = 32; off > 0; off >>= 1) {
    s += __shfl_xor(s, off);
    ss += __shfl_xor(ss, off);
  }
  __shared__ float rs[4], rss[4];
  int w = t >> 6;
  if ((t & 63) == 0) { rs[w] = s; rss[w] = ss; }
  __syncthreads();
  s = rs[0] + rs[1] + rs[2] + rs[3];
  ss = rss[0] + rss[1] + rss[2] + rss[3];
  const float invn = 1.f / (16 * HW);
  float mean = s * invn;
  float var = ss * invn - mean * mean;
  float rstd = rsqrtf(var + EPS);
  float a_[16], b_[16];
#pragma unroll
  for (int c = 0; c < 16; ++c) {
    float gm = gamma[g * 16 + c] * rstd;
    a_[c] = gm;
    b_[c] = beta[g * 16 + c] - mean * gm;
  }
#pragma unroll
  for (int i = 0; i < 4; ++i) {
    int p = 4 * t + i;
    uint4 u0, u1;
    u0.x = cvt_pk_bf16(vv[0][i] * a_[0] + b_[0], vv[1][i] * a_[1] + b_[1]);
    u0.y = cvt_pk_bf16(vv[2][i] * a_[2] + b_[2], vv[3][i] * a_[3] + b_[3]);
    u0.z = cvt_pk_bf16(vv[4][i] * a_[4] + b_[4], vv[5][i] * a_[5] + b_[5]);
    u0.w = cvt_pk_bf16(vv[6][i] * a_[6] + b_[6], vv[7][i] * a_[7] + b_[7]);
    u1.x = cvt_pk_bf16(vv[8][i] * a_[8] + b_[8], vv[9][i] * a_[9] + b_[9]);
    u1.y = cvt_pk_bf16(vv[10][i] * a_[10] + b_[10], vv[11][i] * a_[11] + b_[11]);
    u1.z = cvt_pk_bf16(vv[12][i] * a_[12] + b_[12], vv[13][i] * a_[13] + b_[13]);
    u1.w = cvt_pk_bf16(vv[14][i] * a_[14] + b_[14], vv[15][i] * a_[15] + b_[15]);
    unsigned short* dst = hn + ((size_t)b * HW + p) * CCH + g * 16;
    *(uint4*)dst = u0;
    *(uint4*)(dst + 8) = u1;
  }
}

// ---------- MFMA GEMM, m97-style staging (global_load_lds + XOR swizzle) ---
// D[pos][ch] = sum_k Xt[b][pos][k] * W[ch][k] + bias
// PROJ=0: fused QKV: mat 0 -> pos-major bf16 * QSCALE (Q); mat 1 -> pos-major
//         (K); mat 2 -> ch-major (V).
// PROJ=1: fp32 ch-major out + residual.
template <int PROJ>
__global__ __launch_bounds__(256, 3) void mm_kernel(
    const unsigned short* __restrict__ Xt, const unsigned short* __restrict__ Wb,
    const float* __restrict__ b0, const float* __restrict__ b1,
    const float* __restrict__ b2, const float* __restrict__ resid,
    unsigned short* __restrict__ O0, unsigned short* __restrict__ O1,
    unsigned short* __restrict__ O2, float* __restrict__ Ofp) {
  int b = blockIdx.z;
  int p0 = blockIdx.x * 128;
  int c0g = blockIdx.y * 128;
  __shared__ __align__(16) unsigned short Xs[128 * 32];
  __shared__ __align__(16) unsigned short Ws[128 * 32];
  int t = threadIdx.x;
  int w = t >> 6, lane = t & 63, l15 = lane & 15, quad = lane >> 4;
  int wp = (w & 1) * 64, wc = (w >> 1) * 64;
  const unsigned short* Xb = Xt + (size_t)b * HW * CCH;
  const unsigned short* Wr = Wb + (size_t)c0g * CCH;
  f4 acc[4][4] = {};
  for (int k0 = 0; k0 < CCH; k0 += 32) {
    __syncthreads();
#pragma unroll
    for (int j = 0; j < 2; ++j) {
      int chk = w * 2 + j;             // 1KB chunk = 16 rows x 64B
      int r = chk * 16 + (lane >> 2);
      int c = (lane & 3) ^ (r & 3);    // XOR swizzle
      ldg_lds16(&Xb[(size_t)(p0 + r) * CCH + k0 + c * 8], &Xs[chk * 512]);
      ldg_lds16(&Wr[(size_t)r * CCH + k0 + c * 8], &Ws[chk * 512]);
    }
    __syncthreads();
    bfrag af[4], bf[4];
#pragma unroll
    for (int pt = 0; pt < 4; ++pt) {
      int r = wp + pt * 16 + l15;
      af[pt] = *(const bfrag*)&Xs[r * 32 + (quad ^ (r & 3)) * 8];
    }
#pragma unroll
    for (int ct = 0; ct < 4; ++ct) {
      int r = wc + ct * 16 + l15;
      bf[ct] = *(const bfrag*)&Ws[r * 32 + (quad ^ (r & 3)) * 8];
    }
#pragma unroll
    for (int pt = 0; pt < 4; ++pt)
#pragma unroll
      for (int ct = 0; ct < 4; ++ct)
        acc[pt][ct] = __builtin_amdgcn_mfma_f32_16x16x32_bf16(
            af[pt], bf[ct], acc[pt][ct], 0, 0, 0);
  }
  if (PROJ) {
#pragma unroll
    for (int ct = 0; ct < 4; ++ct) {
      int ch = c0g + wc + ct * 16 + l15;
      float bi = b0[ch];
#pragma unroll
      for (int pt = 0; pt < 4; ++pt) {
        int pos = p0 + wp + pt * 16 + quad * 4;
        f4 v = acc[pt][ct];
        size_t off = (size_t)b * CCH * HW + (size_t)ch * HW + pos;
        float4 rv = *(const float4*)&resid[off];
        float4 st;
        st.x = v.x + bi + rv.x; st.y = v.y + bi + rv.y;
        st.z = v.z + bi + rv.z; st.w = v.w + bi + rv.w;
        *(float4*)&Ofp[off] = st;
      }
    }
  } else {
    int mat = c0g >> 9;
    int c0 = c0g & 511;
    const float* bias = mat == 0 ? b0 : (mat == 1 ? b1 : b2);
    unsigned short* O = mat == 0 ? O0 : (mat == 1 ? O1 : O2);
    const float sc = (mat == 0) ? QSCALE : 1.0f;
#pragma unroll
    for (int ct = 0; ct < 4; ++ct) {
      int ch = c0 + wc + ct * 16 + l15;
      float bi = bias[ch];
#pragma unroll
      for (int pt = 0; pt < 4; ++pt) {
        int pos = p0 + wp + pt * 16 + quad * 4;
        f4 v = acc[pt][ct];
        if (mat < 2) {  // pos-major; lanes (l15) -> consecutive ch: 32B segs
          unsigned short* Op = O + (size_t)b * HW * CCH;
          Op[(size_t)(pos + 0) * CCH + ch] = f2bf((v.x + bi) * sc);
          Op[(size_t)(pos + 1) * CCH + ch] = f2bf((v.y + bi) * sc);
          Op[(size_t)(pos + 2) * CCH + ch] = f2bf((v.z + bi) * sc);
          Op[(size_t)(pos + 3) * CCH + ch] = f2bf((v.w + bi) * sc);
        } else {  // ch-major (V): quad-contiguous pos -> 64B segs
          unsigned short* Op = O + (size_t)b * CCH * HW;
          ushort4 st;
          st.x = f2bf(v.x + bi); st.y = f2bf(v.y + bi);
          st.z = f2bf(v.z + bi); st.w = f2bf(v.w + bi);
          *(ushort4*)&Op[(size_t)ch * HW + pos] = st;
        }
      }
    }
  }
}

// ---------- Flash attention: 512 thr, q-block 128, kk-split specialization -
// 8 waves = 4 q-groups x 2 kk-halves. Each wave does half the kk rows of each
// K/V tile (halved per-wave LDS reads + dep chains); partial (o,l) combined
// via LDS at the end (fixed-base softmax -> partials sum exactly).
// 64KB LDS, __launch_bounds__(512,4): 2 blk/CU, 16 waves/CU (4/SIMD).
__global__ __launch_bounds__(512, 4) void attn_kernel(
    const unsigned short* __restrict__ Qt, const unsigned short* __restrict__ Kt,
    const unsigned short* __restrict__ Vc, unsigned short* __restrict__ Ot) {
  int bh = blockIdx.x;
  int b = bh >> 2, h = bh & 3;
  int q0 = blockIdx.y * 128;
  int t = threadIdx.x;
  int w = t >> 6, lane = t & 63;
  int l31 = lane & 31, half = lane >> 5;
  int qg = w & 3, kh = w >> 2;
  // 64KB: Ks[2] = S_[0..16K), Vs[2] = S_[16K..32K) (ushort idx); reused as
  // the fp32 combine buffer after the kt loop.
  __shared__ __align__(16) unsigned short S_[32768];
  int q = q0 + qg * 32 + l31;  // this lane's query
  const unsigned short* Kbase = Kt + (size_t)b * HW * CCH + h * HD;
  const unsigned short* Vbase = Vc + ((size_t)b * CCH + h * HD) * HW;
  // Q B-frags: B[k=ks*16+half*8+j][n=q], loop-invariant
  bfrag qf[8];
#pragma unroll
  for (int ks = 0; ks < 8; ++ks)
    qf[ks] = *(const bfrag*)&Qt[((size_t)b * HW + q) * CCH + h * HD +
                                ks * 16 + half * 8];
  f16v o[4] = {};   // PV accum for this kk-half: D[m=d (4x32)][n=q]
  float ls[4] = {}; // rotating partial row-sums
  // staging: wave w owns chunks 2w,2w+1 of K tile and of V tile (1KB each)
  auto stage = [&](int kt, int bi) {
    int kk0 = kt * 64;
    unsigned short* Kd = S_ + bi * 8192;
    unsigned short* Vd = S_ + 16384 + bi * 8192;
#pragma unroll
    for (int j = 0; j < 2; ++j) {
      int chk = w * 2 + j;
      {  // K chunk: 4 rows x 256B
        int r = chk * 4 + (lane >> 4);
        int c = (lane & 15) ^ (r & 15);
        ldg_lds16(&Kbase[(size_t)(kk0 + r) * CCH + c * 8], Kd + chk * 512);
      }
      {  // V chunk: 8 rows x 128B
        int r = chk * 8 + (lane >> 3);
        int c = (lane & 7) ^ (r & 7);
        ldg_lds16(&Vbase[(size_t)r * HW + kk0 + c * 8], Vd + chk * 512);
      }
    }
  };
  stage(0, 0);
  for (int kt = 0; kt < 16; ++kt) {
    __syncthreads();  // stage(kt) complete everywhere; prev-iter reads done
    if (kt < 15) stage(kt + 1, (kt + 1) & 1);  // overlaps compute below
    const unsigned short* K_ = S_ + (kt & 1) * 8192;
    const unsigned short* V_ = S_ + 16384 + (kt & 1) * 8192;
    // QK^T on this wave's kk-half: D[m=kk 32][n=q 32]
    f16v S = {};
    __builtin_amdgcn_s_setprio(1);
#pragma unroll
    for (int ks = 0; ks < 8; ++ks) {
      int c16 = ks * 2 + half;
      int r = kh * 32 + l31;
      bfrag kf = *(const bfrag*)&K_[r * 128 + ((c16 ^ (r & 15)) << 3)];
      S = __builtin_amdgcn_mfma_f32_32x32x16_bf16(kf, qf[ks], S, 0, 0, 0);
    }
    __builtin_amdgcn_s_setprio(0);
    // exp2 softmax: p = 2^S (log2e folded into Q scale -> exact e^s softmax)
    unsigned pd[8];
#pragma unroll
    for (int i = 0; i < 8; ++i) {
      float p0 = EXP2(S[2 * i]);
      float p1 = EXP2(S[2 * i + 1]);
      ls[i & 3] += p0 + p1;
      pd[i] = cvt_pk_bf16(p0, p1);
    }
    // P C-layout -> B-layout: one v_permlane32_swap per reg pair.
    // swap(pd0,pd2): pd0 := {lo: own pd0, hi: pd2 from lane-32} = u0
    //                pd2 := {lo: pd0 from lane+32, hi: own pd2} = u2
#pragma unroll
    for (int s = 0; s < 2; ++s) {
      unsigned a0 = pd[s * 4 + 0], a1 = pd[s * 4 + 1];
      unsigned c0 = pd[s * 4 + 2], c1 = pd[s * 4 + 3];
      asm("v_permlane32_swap_b32 %0, %1" : "+v"(a0), "+v"(c0));
      asm("v_permlane32_swap_b32 %0, %1" : "+v"(a1), "+v"(c1));
      union { unsigned u[4]; bfrag f; } pf;
      pf.u[0] = a0; pf.u[1] = a1; pf.u[2] = c0; pf.u[3] = c1;
      int c8 = (kh * 2 + s) * 2 + half;
      __builtin_amdgcn_s_setprio(1);
#pragma unroll
      for (int dt = 0; dt < 4; ++dt) {
        int r = dt * 32 + l31;
        bfrag vf = *(const bfrag*)&V_[r * 64 + ((c8 ^ (r & 7)) << 3)];
        o[dt] = __builtin_amdgcn_mfma_f32_32x32x16_bf16(vf, pf.f, o[dt],
                                                        0, 0, 0);
      }
      __builtin_amdgcn_s_setprio(0);
    }
  }
  // intra-wave: lane and lane^32 own complementary kk rows of this half
  float lrow = (ls[0] + ls[1]) + (ls[2] + ls[3]);
  lrow += __shfl_xor(lrow, 32);
  // ---- cross-kh combine (fixed-base softmax: partials sum exactly) ----
  __syncthreads();                     // all tile reads done; LDS reusable
  float* lb = (float*)S_;
  if (kh == 1 && half == 0) lb[qg * 32 + l31] = lrow;
  __syncthreads();
  if (kh == 0) lrow += lb[qg * 32 + l31];
  __syncthreads();
  float* ob = (float*)S_;              // 16K floats: [qg][q 32][d 128] swz
  if (kh == 1) {
#pragma unroll
    for (int dt = 0; dt < 4; ++dt) {
      union { f16v v; f4 q4[4]; } u; u.v = o[dt];
#pragma unroll
      for (int rg = 0; rg < 4; ++rg) {
        int d4 = dt * 8 + rg * 2 + half;  // d>>2 (16B granule)
        *(f4*)&ob[qg * 4096 + l31 * 128 + ((d4 ^ (l31 & 7)) << 2)] = u.q4[rg];
      }
    }
  }
  __syncthreads();
  if (kh == 0) {
    float inv = 1.f / lrow;
    unsigned short* Op = Ot + ((size_t)b * HW + q) * CCH + h * HD;
#pragma unroll
    for (int dt = 0; dt < 4; ++dt) {
      union { f16v v; f4 q4[4]; } u; u.v = o[dt];
#pragma unroll
      for (int rg = 0; rg < 4; ++rg) {
        int d4 = dt * 8 + rg * 2 + half;
        f4 oth = *(const f4*)&ob[qg * 4096 + l31 * 128 +
                                 ((d4 ^ (l31 & 7)) << 2)];
        f4 mine = u.q4[rg];
        int d = d4 << 2;
        uint2 st;
        st.x = cvt_pk_bf16((mine.x + oth.x) * inv, (mine.y + oth.y) * inv);
        st.y = cvt_pk_bf16((mine.z + oth.z) * inv, (mine.w + oth.w) * inv);
        *(uint2*)&Op[d] = st;
      }
    }
  }
}

extern "C" void kernel_launch(void* const* d_in, const int* in_sizes, int n_in,
                              void* d_out, int out_size, void* d_ws,
                              size_t ws_size, hipStream_t stream) {
  const float* x = (const float*)d_in[0];
  const float* gamma = (const float*)d_in[1];
  const float* beta = (const float*)d_in[2];
  const float* wq = (const float*)d_in[3];
  const float* bq = (const float*)d_in[4];
  const float* wk = (const float*)d_in[5];
  const float* bk = (const float*)d_in[6];
  const float* wv = (const float*)d_in[7];
  const float* bv = (const float*)d_in[8];
  const float* wp = (const float*)d_in[9];
  const float* bp = (const float*)d_in[10];

  const size_t TS = (size_t)BATCH * HW * CCH;
  unsigned short* wB = (unsigned short*)d_ws;  // [4][512][512] bf16 (q,k,v,p)
  unsigned short* hn = wB + (size_t)4 * CCH * CCH;
  unsigned short* Qt = hn + TS;
  unsigned short* Kt = Qt + TS;
  unsigned short* Vc = Kt + TS;
  unsigned short* Ot = hn;  // reuse hn after QKV

  wcvt_kernel<<<dim3(256, 4), 256, 0, stream>>>(wq, wk, wv, wp, wB);
  gn_kernel<<<dim3(BATCH * 32), 256, 0, stream>>>(x, gamma, beta, hn);
  mm_kernel<0><<<dim3(8, 12, BATCH), 256, 0, stream>>>(
      hn, wB, bq, bk, bv, nullptr, Qt, Kt, Vc, nullptr);
  attn_kernel<<<dim3(64, 8), 512, 0, stream>>>(Qt, Kt, Vc, Ot);
  mm_kernel<1><<<dim3(8, 4, BATCH), 256, 0, stream>>>(
      Ot, wB + (size_t)3 * CCH * CCH, bp, bp, bp, x, nullptr, nullptr, nullptr,
      (float*)d_out);
}

// Round 3
// 219.606 us; speedup vs baseline: 1.1272x; 1.1272x over previous
//
#include <hip/hip_runtime.h>
#include <math.h>

#define CCH 512
#define NH 4
#define HD 128
#define HW 1024
#define BATCH 16
#define EPS 1e-5f

typedef __attribute__((ext_vector_type(8))) short bfrag;    // 8 bf16 = 4 VGPRs
typedef __attribute__((ext_vector_type(4))) float f4;
typedef __attribute__((ext_vector_type(16))) float f16v;    // 32x32 accum

static __device__ __forceinline__ unsigned short f2bf(float f) {
  union { float f; unsigned u; } v;
  v.f = f;
  unsigned r = v.u + 0x7fff + ((v.u >> 16) & 1);  // RNE
  return (unsigned short)(r >> 16);
}
static __device__ __forceinline__ unsigned pack2(unsigned short a, unsigned short b) {
  return (unsigned)a | ((unsigned)b << 16);
}
// packed f32x2 -> bf16x2 in one VALU op (gfx950). src0 -> low half.
static __device__ __forceinline__ unsigned cvt_pk_bf16(float a, float b) {
  unsigned r;
  asm("v_cvt_pk_bf16_f32 %0, %1, %2" : "=v"(r) : "v"(a), "v"(b));
  return r;
}
// exp2 via HW transcendental (no log2e multiply; folded into Q scale)
#if defined(__has_builtin) && __has_builtin(__builtin_amdgcn_exp2f)
#define EXP2(x) __builtin_amdgcn_exp2f(x)
#else
#define EXP2(x) __expf((x) * 0.6931471805599453f)  // e^(x ln2) == 2^x
#endif
// async global->LDS, 16B/lane. LDS dest = wave-uniform base + lane*16.
static __device__ __forceinline__ void ldg_lds16(const unsigned short* g,
                                                 unsigned short* l) {
  __builtin_amdgcn_global_load_lds(
      (const __attribute__((address_space(1))) unsigned int*)g,
      (__attribute__((address_space(3))) unsigned int*)l, 16, 0, 0);
}

// softmax scale folded into Q GEMM epilogue. Includes log2(e) so the
// attention softmax can use raw v_exp_f32 (2^x): 2^(s*log2e) == e^s exactly.
#define QSCALE (0.08838834764831845f * 1.4426950408889634f)

// ---------- weights fp32 -> bf16 (4 matrices stacked) ----------
__global__ __launch_bounds__(256) void wcvt_kernel(const float* __restrict__ s0,
                                                   const float* __restrict__ s1,
                                                   const float* __restrict__ s2,
                                                   const float* __restrict__ s3,
                                                   unsigned short* __restrict__ d) {
  const float* srcs[4] = {s0, s1, s2, s3};
  const float* s = srcs[blockIdx.y];
  unsigned short* dp = d + (size_t)blockIdx.y * CCH * CCH;
  int i = blockIdx.x * 256 + threadIdx.x;
  f4 v = ((const f4*)s)[i];
  ushort4 o;
  o.x = f2bf(v.x); o.y = f2bf(v.y); o.z = f2bf(v.z); o.w = f2bf(v.w);
  ((ushort4*)dp)[i] = o;
}

// ---------- GroupNorm -> position-major bf16 hn_t[b][hw][c] ----------
// Single global read: thread t holds channels 0..15 at positions 4t..4t+3 in
// registers (64 floats); stats via shuffle; write directly from registers.
__global__ __launch_bounds__(256) void gn_kernel(const float* __restrict__ x,
                                                 const float* __restrict__ gamma,
                                                 const float* __restrict__ beta,
                                                 unsigned short* __restrict__ hn) {
  int b = blockIdx.x >> 5, g = blockIdx.x & 31;
  const float* xp = x + ((size_t)b * CCH + g * 16) * HW;
  int t = threadIdx.x;
  float s = 0.f, ss = 0.f;
  const f4* xp4 = (const f4*)xp;
  f4 vv[16];
#pragma unroll
  for (int c = 0; c < 16; ++c) {
    f4 v = xp4[c * 256 + t];  // channel c, positions 4t..4t+3
    vv[c] = v;
    s += v.x + v.y + v.z + v.w;
    ss += v.x * v.x + v.y * v.y + v.z * v.z + v.w * v.w;
  }
#pragma unroll
  for (int off = 32; off > 0; off >>= 1) {
    s += __shfl_xor(s, off);
    ss += __shfl_xor(ss, off);
  }
  __shared__ float rs[4], rss[4];
  int w = t >> 6;
  if ((t & 63) == 0) { rs[w] = s; rss[w] = ss; }
  __syncthreads();
  s = rs[0] + rs[1] + rs[2] + rs[3];
  ss = rss[0] + rss[1] + rss[2] + rss[3];
  const float invn = 1.f / (16 * HW);
  float mean = s * invn;
  float var = ss * invn - mean * mean;
  float rstd = rsqrtf(var + EPS);
  float a_[16], b_[16];
#pragma unroll
  for (int c = 0; c < 16; ++c) {
    float gm = gamma[g * 16 + c] * rstd;
    a_[c] = gm;
    b_[c] = beta[g * 16 + c] - mean * gm;
  }
#pragma unroll
  for (int i = 0; i < 4; ++i) {
    int p = 4 * t + i;
    uint4 u0, u1;
    u0.x = cvt_pk_bf16(vv[0][i] * a_[0] + b_[0], vv[1][i] * a_[1] + b_[1]);
    u0.y = cvt_pk_bf16(vv[2][i] * a_[2] + b_[2], vv[3][i] * a_[3] + b_[3]);
    u0.z = cvt_pk_bf16(vv[4][i] * a_[4] + b_[4], vv[5][i] * a_[5] + b_[5]);
    u0.w = cvt_pk_bf16(vv[6][i] * a_[6] + b_[6], vv[7][i] * a_[7] + b_[7]);
    u1.x = cvt_pk_bf16(vv[8][i] * a_[8] + b_[8], vv[9][i] * a_[9] + b_[9]);
    u1.y = cvt_pk_bf16(vv[10][i] * a_[10] + b_[10], vv[11][i] * a_[11] + b_[11]);
    u1.z = cvt_pk_bf16(vv[12][i] * a_[12] + b_[12], vv[13][i] * a_[13] + b_[13]);
    u1.w = cvt_pk_bf16(vv[14][i] * a_[14] + b_[14], vv[15][i] * a_[15] + b_[15]);
    unsigned short* dst = hn + ((size_t)b * HW + p) * CCH + g * 16;
    *(uint4*)dst = u0;
    *(uint4*)(dst + 8) = u1;
  }
}

// ---------- MFMA GEMM, m97-style staging (global_load_lds + XOR swizzle) ---
// D[pos][ch] = sum_k Xt[b][pos][k] * W[ch][k] + bias
// PROJ=0: fused QKV: mat 0 -> pos-major bf16 * QSCALE (Q); mat 1 -> pos-major
//         (K); mat 2 -> ch-major (V).
// PROJ=1: fp32 ch-major out + residual.
template <int PROJ>
__global__ __launch_bounds__(256, 3) void mm_kernel(
    const unsigned short* __restrict__ Xt, const unsigned short* __restrict__ Wb,
    const float* __restrict__ b0, const float* __restrict__ b1,
    const float* __restrict__ b2, const float* __restrict__ resid,
    unsigned short* __restrict__ O0, unsigned short* __restrict__ O1,
    unsigned short* __restrict__ O2, float* __restrict__ Ofp) {
  int b = blockIdx.z;
  int p0 = blockIdx.x * 128;
  int c0g = blockIdx.y * 128;
  __shared__ __align__(16) unsigned short Xs[128 * 32];
  __shared__ __align__(16) unsigned short Ws[128 * 32];
  int t = threadIdx.x;
  int w = t >> 6, lane = t & 63, l15 = lane & 15, quad = lane >> 4;
  int wp = (w & 1) * 64, wc = (w >> 1) * 64;
  const unsigned short* Xb = Xt + (size_t)b * HW * CCH;
  const unsigned short* Wr = Wb + (size_t)c0g * CCH;
  f4 acc[4][4] = {};
  for (int k0 = 0; k0 < CCH; k0 += 32) {
    __syncthreads();
#pragma unroll
    for (int j = 0; j < 2; ++j) {
      int chk = w * 2 + j;             // 1KB chunk = 16 rows x 64B
      int r = chk * 16 + (lane >> 2);
      int c = (lane & 3) ^ (r & 3);    // XOR swizzle
      ldg_lds16(&Xb[(size_t)(p0 + r) * CCH + k0 + c * 8], &Xs[chk * 512]);
      ldg_lds16(&Wr[(size_t)r * CCH + k0 + c * 8], &Ws[chk * 512]);
    }
    __syncthreads();
    bfrag af[4], bf[4];
#pragma unroll
    for (int pt = 0; pt < 4; ++pt) {
      int r = wp + pt * 16 + l15;
      af[pt] = *(const bfrag*)&Xs[r * 32 + (quad ^ (r & 3)) * 8];
    }
#pragma unroll
    for (int ct = 0; ct < 4; ++ct) {
      int r = wc + ct * 16 + l15;
      bf[ct] = *(const bfrag*)&Ws[r * 32 + (quad ^ (r & 3)) * 8];
    }
#pragma unroll
    for (int pt = 0; pt < 4; ++pt)
#pragma unroll
      for (int ct = 0; ct < 4; ++ct)
        acc[pt][ct] = __builtin_amdgcn_mfma_f32_16x16x32_bf16(
            af[pt], bf[ct], acc[pt][ct], 0, 0, 0);
  }
  if (PROJ) {
#pragma unroll
    for (int ct = 0; ct < 4; ++ct) {
      int ch = c0g + wc + ct * 16 + l15;
      float bi = b0[ch];
#pragma unroll
      for (int pt = 0; pt < 4; ++pt) {
        int pos = p0 + wp + pt * 16 + quad * 4;
        f4 v = acc[pt][ct];
        size_t off = (size_t)b * CCH * HW + (size_t)ch * HW + pos;
        float4 rv = *(const float4*)&resid[off];
        float4 st;
        st.x = v.x + bi + rv.x; st.y = v.y + bi + rv.y;
        st.z = v.z + bi + rv.z; st.w = v.w + bi + rv.w;
        *(float4*)&Ofp[off] = st;
      }
    }
  } else {
    int mat = c0g >> 9;
    int c0 = c0g & 511;
    const float* bias = mat == 0 ? b0 : (mat == 1 ? b1 : b2);
    unsigned short* O = mat == 0 ? O0 : (mat == 1 ? O1 : O2);
    const float sc = (mat == 0) ? QSCALE : 1.0f;
#pragma unroll
    for (int ct = 0; ct < 4; ++ct) {
      int ch = c0 + wc + ct * 16 + l15;
      float bi = bias[ch];
#pragma unroll
      for (int pt = 0; pt < 4; ++pt) {
        int pos = p0 + wp + pt * 16 + quad * 4;
        f4 v = acc[pt][ct];
        if (mat < 2) {  // pos-major; lanes (l15) -> consecutive ch: 32B segs
          unsigned short* Op = O + (size_t)b * HW * CCH;
          Op[(size_t)(pos + 0) * CCH + ch] = f2bf((v.x + bi) * sc);
          Op[(size_t)(pos + 1) * CCH + ch] = f2bf((v.y + bi) * sc);
          Op[(size_t)(pos + 2) * CCH + ch] = f2bf((v.z + bi) * sc);
          Op[(size_t)(pos + 3) * CCH + ch] = f2bf((v.w + bi) * sc);
        } else {  // ch-major (V): quad-contiguous pos -> 64B segs
          unsigned short* Op = O + (size_t)b * CCH * HW;
          ushort4 st;
          st.x = f2bf(v.x + bi); st.y = f2bf(v.y + bi);
          st.z = f2bf(v.z + bi); st.w = f2bf(v.w + bi);
          *(ushort4*)&Op[(size_t)ch * HW + pos] = st;
        }
      }
    }
  }
}

// ---------- Flash attention: 256 thr, q-tile 64, kk-split, 3 waves/SIMD ----
// 4 waves = 2 q-groups x 2 kk-halves; each wave does half the kk rows per
// tile (partials combine exactly: fixed-base softmax). LDS 48KB = K dbuf
// (2x16KB) + V single (16KB) -> 3 blocks/CU. __launch_bounds__(256,3) caps
// regs at ~170 (live ~155, no spill) -> 12 waves/CU (3/SIMD).
// Per kt: [syncthreads: drains K[kt]] stage V[kt]; stage K[kt+1]; QK^T from
// K dbuf; softmax; vmcnt(4) (V done, K in flight) + raw barrier; PV.
__global__ __launch_bounds__(256, 3) void attn_kernel(
    const unsigned short* __restrict__ Qt, const unsigned short* __restrict__ Kt,
    const unsigned short* __restrict__ Vc, unsigned short* __restrict__ Ot) {
  int bh = blockIdx.x;
  int b = bh >> 2, h = bh & 3;
  int q0 = blockIdx.y * 64;
  int t = threadIdx.x;
  int w = t >> 6, lane = t & 63;
  int l31 = lane & 31, half = lane >> 5;
  int qg = w & 1, kh = w >> 1;
  // 48KB: K dbuf = S_[0..16384), V = S_[16384..24576) (ushort idx); fp32
  // combine buffer reuses the same region after the kt loop.
  __shared__ __align__(16) unsigned short S_[24576];
  int q = q0 + qg * 32 + l31;  // this lane's query
  const unsigned short* Kbase = Kt + (size_t)b * HW * CCH + h * HD;
  const unsigned short* Vbase = Vc + ((size_t)b * CCH + h * HD) * HW;
  // Q B-frags: B[k=ks*16+half*8+j][n=q], loop-invariant
  bfrag qf[8];
#pragma unroll
  for (int ks = 0; ks < 8; ++ks)
    qf[ks] = *(const bfrag*)&Qt[((size_t)b * HW + q) * CCH + h * HD +
                                ks * 16 + half * 8];
  f16v o[4] = {};   // PV accum for this kk-half: D[m=d (4x32)][n=q]
  float ls[4] = {}; // rotating partial row-sums
  // K tile: 16KB = 16 chunks (4 rows x 256B); wave stages chunks 4w..4w+3
  auto stageK = [&](int kt, int bi) {
    int kk0 = kt * 64;
    unsigned short* Kd = S_ + bi * 8192;
#pragma unroll
    for (int j = 0; j < 4; ++j) {
      int chk = w * 4 + j;
      int r = chk * 4 + (lane >> 4);
      int c = (lane & 15) ^ (r & 15);
      ldg_lds16(&Kbase[(size_t)(kk0 + r) * CCH + c * 8], Kd + chk * 512);
    }
  };
  // V tile: 16KB = 16 chunks (8 rows x 128B); wave stages chunks 4w..4w+3
  auto stageV = [&](int kt) {
    int kk0 = kt * 64;
    unsigned short* Vd = S_ + 16384;
#pragma unroll
    for (int j = 0; j < 4; ++j) {
      int chk = w * 4 + j;
      int r = chk * 8 + (lane >> 3);
      int c = (lane & 7) ^ (r & 7);
      ldg_lds16(&Vbase[(size_t)r * HW + kk0 + c * 8], Vd + chk * 512);
    }
  };
  stageK(0, 0);
  for (int kt = 0; kt < 16; ++kt) {
    // full drain + barrier: K[kt] staged everywhere; V/PV of kt-1 done
    __syncthreads();
    stageV(kt);                      // V single buffer (issue first)
    if (kt < 15) stageK(kt + 1, (kt + 1) & 1);
    const unsigned short* K_ = S_ + (kt & 1) * 8192;
    // QK^T on this wave's kk-half: D[m=kk 32][n=q 32]
    f16v S = {};
    __builtin_amdgcn_s_setprio(1);
#pragma unroll
    for (int ks = 0; ks < 8; ++ks) {
      int c16 = ks * 2 + half;
      int r = kh * 32 + l31;
      bfrag kf = *(const bfrag*)&K_[r * 128 + ((c16 ^ (r & 15)) << 3)];
      S = __builtin_amdgcn_mfma_f32_32x32x16_bf16(kf, qf[ks], S, 0, 0, 0);
    }
    __builtin_amdgcn_s_setprio(0);
    // exp2 softmax: p = 2^S (log2e folded into Q scale -> exact e^s softmax)
    unsigned pd[8];
#pragma unroll
    for (int i = 0; i < 8; ++i) {
      float p0 = EXP2(S[2 * i]);
      float p1 = EXP2(S[2 * i + 1]);
      ls[i & 3] += p0 + p1;
      pd[i] = cvt_pk_bf16(p0, p1);
    }
    // V[kt] ready: own 4 V-loads retired (4 K-loads may stay in flight),
    // then barrier makes all waves' V writes visible. Raw barrier: no
    // compiler-inserted vmcnt(0), so K[kt+1] prefetch spans the barrier.
    if (kt < 15)
      asm volatile("s_waitcnt vmcnt(4)" ::: "memory");
    else
      asm volatile("s_waitcnt vmcnt(0)" ::: "memory");
    __builtin_amdgcn_s_barrier();
    __builtin_amdgcn_sched_barrier(0);
    const unsigned short* V_ = S_ + 16384;
    // P C-layout -> B-layout: one v_permlane32_swap per reg pair.
#pragma unroll
    for (int s = 0; s < 2; ++s) {
      unsigned a0 = pd[s * 4 + 0], a1 = pd[s * 4 + 1];
      unsigned c0 = pd[s * 4 + 2], c1 = pd[s * 4 + 3];
      asm("v_permlane32_swap_b32 %0, %1" : "+v"(a0), "+v"(c0));
      asm("v_permlane32_swap_b32 %0, %1" : "+v"(a1), "+v"(c1));
      union { unsigned u[4]; bfrag f; } pf;
      pf.u[0] = a0; pf.u[1] = a1; pf.u[2] = c0; pf.u[3] = c1;
      int c8 = (kh * 2 + s) * 2 + half;
      __builtin_amdgcn_s_setprio(1);
#pragma unroll
      for (int dt = 0; dt < 4; ++dt) {
        int r = dt * 32 + l31;
        bfrag vf = *(const bfrag*)&V_[r * 64 + ((c8 ^ (r & 7)) << 3)];
        o[dt] = __builtin_amdgcn_mfma_f32_32x32x16_bf16(vf, pf.f, o[dt],
                                                        0, 0, 0);
      }
      __builtin_amdgcn_s_setprio(0);
    }
  }
  // intra-wave: lane and lane^32 own complementary kk rows of this half
  float lrow = (ls[0] + ls[1]) + (ls[2] + ls[3]);
  lrow += __shfl_xor(lrow, 32);
  // ---- cross-kh combine (fixed-base softmax: partials sum exactly) ----
  __syncthreads();                     // all tile reads done; LDS reusable
  float* ob = (float*)S_;              // [qg][q 32][d 128] swizzled, 32KB
  float* lb = (float*)S_ + 8192;       // 64 floats at byte 32768 (disjoint)
  if (kh == 1) {
    if (half == 0) lb[qg * 32 + l31] = lrow;
#pragma unroll
    for (int dt = 0; dt < 4; ++dt) {
      union { f16v v; f4 q4[4]; } u; u.v = o[dt];
#pragma unroll
      for (int rg = 0; rg < 4; ++rg) {
        int d4 = dt * 8 + rg * 2 + half;  // d>>2 (16B granule)
        *(f4*)&ob[qg * 4096 + l31 * 128 + ((d4 ^ (l31 & 7)) << 2)] = u.q4[rg];
      }
    }
  }
  __syncthreads();
  if (kh == 0) {
    lrow += lb[qg * 32 + l31];
    float inv = 1.f / lrow;
    unsigned short* Op = Ot + ((size_t)b * HW + q) * CCH + h * HD;
#pragma unroll
    for (int dt = 0; dt < 4; ++dt) {
      union { f16v v; f4 q4[4]; } u; u.v = o[dt];
#pragma unroll
      for (int rg = 0; rg < 4; ++rg) {
        int d4 = dt * 8 + rg * 2 + half;
        f4 oth = *(const f4*)&ob[qg * 4096 + l31 * 128 +
                                 ((d4 ^ (l31 & 7)) << 2)];
        f4 mine = u.q4[rg];
        int d = d4 << 2;
        uint2 st;
        st.x = cvt_pk_bf16((mine.x + oth.x) * inv, (mine.y + oth.y) * inv);
        st.y = cvt_pk_bf16((mine.z + oth.z) * inv, (mine.w + oth.w) * inv);
        *(uint2*)&Op[d] = st;
      }
    }
  }
}

extern "C" void kernel_launch(void* const* d_in, const int* in_sizes, int n_in,
                              void* d_out, int out_size, void* d_ws,
                              size_t ws_size, hipStream_t stream) {
  const float* x = (const float*)d_in[0];
  const float* gamma = (const float*)d_in[1];
  const float* beta = (const float*)d_in[2];
  const float* wq = (const float*)d_in[3];
  const float* bq = (const float*)d_in[4];
  const float* wk = (const float*)d_in[5];
  const float* bk = (const float*)d_in[6];
  const float* wv = (const float*)d_in[7];
  const float* bv = (const float*)d_in[8];
  const float* wp = (const float*)d_in[9];
  const float* bp = (const float*)d_in[10];

  const size_t TS = (size_t)BATCH * HW * CCH;
  unsigned short* wB = (unsigned short*)d_ws;  // [4][512][512] bf16 (q,k,v,p)
  unsigned short* hn = wB + (size_t)4 * CCH * CCH;
  unsigned short* Qt = hn + TS;
  unsigned short* Kt = Qt + TS;
  unsigned short* Vc = Kt + TS;
  unsigned short* Ot = hn;  // reuse hn after QKV

  wcvt_kernel<<<dim3(256, 4), 256, 0, stream>>>(wq, wk, wv, wp, wB);
  gn_kernel<<<dim3(BATCH * 32), 256, 0, stream>>>(x, gamma, beta, hn);
  mm_kernel<0><<<dim3(8, 12, BATCH), 256, 0, stream>>>(
      hn, wB, bq, bk, bv, nullptr, Qt, Kt, Vc, nullptr);
  attn_kernel<<<dim3(64, 16), 256, 0, stream>>>(Qt, Kt, Vc, Ot);
  mm_kernel<1><<<dim3(8, 4, BATCH), 256, 0, stream>>>(
      Ot, wB + (size_t)3 * CCH * CCH, bp, bp, bp, x, nullptr, nullptr, nullptr,
      (float*)d_out);
}

// Round 4
// 211.419 us; speedup vs baseline: 1.1708x; 1.0387x over previous
//
#include <hip/hip_runtime.h>
#include <math.h>

#define CCH 512
#define NH 4
#define HD 128
#define HW 1024
#define BATCH 16
#define EPS 1e-5f

typedef __attribute__((ext_vector_type(8))) short bfrag;    // 8 bf16 = 4 VGPRs
typedef __attribute__((ext_vector_type(4))) float f4;
typedef __attribute__((ext_vector_type(16))) float f16v;    // 32x32 accum

static __device__ __forceinline__ unsigned short f2bf(float f) {
  union { float f; unsigned u; } v;
  v.f = f;
  unsigned r = v.u + 0x7fff + ((v.u >> 16) & 1);  // RNE
  return (unsigned short)(r >> 16);
}
static __device__ __forceinline__ unsigned pack2(unsigned short a, unsigned short b) {
  return (unsigned)a | ((unsigned)b << 16);
}
// packed f32x2 -> bf16x2 in one VALU op (gfx950). src0 -> low half.
static __device__ __forceinline__ unsigned cvt_pk_bf16(float a, float b) {
  unsigned r;
  asm("v_cvt_pk_bf16_f32 %0, %1, %2" : "=v"(r) : "v"(a), "v"(b));
  return r;
}
// exp2 via HW transcendental (no log2e multiply; folded into Q scale)
#if defined(__has_builtin) && __has_builtin(__builtin_amdgcn_exp2f)
#define EXP2(x) __builtin_amdgcn_exp2f(x)
#else
#define EXP2(x) __expf((x) * 0.6931471805599453f)  // e^(x ln2) == 2^x
#endif
// async global->LDS, 16B/lane. LDS dest = wave-uniform base + lane*16.
static __device__ __forceinline__ void ldg_lds16(const unsigned short* g,
                                                 unsigned short* l) {
  __builtin_amdgcn_global_load_lds(
      (const __attribute__((address_space(1))) unsigned int*)g,
      (__attribute__((address_space(3))) unsigned int*)l, 16, 0, 0);
}

// softmax scale folded into Q GEMM epilogue. Includes log2(e) so the
// attention softmax can use raw v_exp_f32 (2^x): 2^(s*log2e) == e^s exactly.
#define QSCALE (0.08838834764831845f * 1.4426950408889634f)

// ---------- weights fp32 -> bf16 (4 matrices stacked) ----------
__global__ __launch_bounds__(256) void wcvt_kernel(const float* __restrict__ s0,
                                                   const float* __restrict__ s1,
                                                   const float* __restrict__ s2,
                                                   const float* __restrict__ s3,
                                                   unsigned short* __restrict__ d) {
  const float* srcs[4] = {s0, s1, s2, s3};
  const float* s = srcs[blockIdx.y];
  unsigned short* dp = d + (size_t)blockIdx.y * CCH * CCH;
  int i = blockIdx.x * 256 + threadIdx.x;
  f4 v = ((const f4*)s)[i];
  ushort4 o;
  o.x = f2bf(v.x); o.y = f2bf(v.y); o.z = f2bf(v.z); o.w = f2bf(v.w);
  ((ushort4*)dp)[i] = o;
}

// ---------- GroupNorm -> position-major bf16 hn_t[b][hw][c] ----------
// Single global read: thread t holds channels 0..15 at positions 4t..4t+3 in
// registers (64 floats); stats via shuffle; write directly from registers.
__global__ __launch_bounds__(256) void gn_kernel(const float* __restrict__ x,
                                                 const float* __restrict__ gamma,
                                                 const float* __restrict__ beta,
                                                 unsigned short* __restrict__ hn) {
  int b = blockIdx.x >> 5, g = blockIdx.x & 31;
  const float* xp = x + ((size_t)b * CCH + g * 16) * HW;
  int t = threadIdx.x;
  float s = 0.f, ss = 0.f;
  const f4* xp4 = (const f4*)xp;
  f4 vv[16];
#pragma unroll
  for (int c = 0; c < 16; ++c) {
    f4 v = xp4[c * 256 + t];  // channel c, positions 4t..4t+3
    vv[c] = v;
    s += v.x + v.y + v.z + v.w;
    ss += v.x * v.x + v.y * v.y + v.z * v.z + v.w * v.w;
  }
#pragma unroll
  for (int off = 32; off > 0; off >>= 1) {
    s += __shfl_xor(s, off);
    ss += __shfl_xor(ss, off);
  }
  __shared__ float rs[4], rss[4];
  int w = t >> 6;
  if ((t & 63) == 0) { rs[w] = s; rss[w] = ss; }
  __syncthreads();
  s = rs[0] + rs[1] + rs[2] + rs[3];
  ss = rss[0] + rss[1] + rss[2] + rss[3];
  const float invn = 1.f / (16 * HW);
  float mean = s * invn;
  float var = ss * invn - mean * mean;
  float rstd = rsqrtf(var + EPS);
  float a_[16], b_[16];
#pragma unroll
  for (int c = 0; c < 16; ++c) {
    float gm = gamma[g * 16 + c] * rstd;
    a_[c] = gm;
    b_[c] = beta[g * 16 + c] - mean * gm;
  }
#pragma unroll
  for (int i = 0; i < 4; ++i) {
    int p = 4 * t + i;
    uint4 u0, u1;
    u0.x = cvt_pk_bf16(vv[0][i] * a_[0] + b_[0], vv[1][i] * a_[1] + b_[1]);
    u0.y = cvt_pk_bf16(vv[2][i] * a_[2] + b_[2], vv[3][i] * a_[3] + b_[3]);
    u0.z = cvt_pk_bf16(vv[4][i] * a_[4] + b_[4], vv[5][i] * a_[5] + b_[5]);
    u0.w = cvt_pk_bf16(vv[6][i] * a_[6] + b_[6], vv[7][i] * a_[7] + b_[7]);
    u1.x = cvt_pk_bf16(vv[8][i] * a_[8] + b_[8], vv[9][i] * a_[9] + b_[9]);
    u1.y = cvt_pk_bf16(vv[10][i] * a_[10] + b_[10], vv[11][i] * a_[11] + b_[11]);
    u1.z = cvt_pk_bf16(vv[12][i] * a_[12] + b_[12], vv[13][i] * a_[13] + b_[13]);
    u1.w = cvt_pk_bf16(vv[14][i] * a_[14] + b_[14], vv[15][i] * a_[15] + b_[15]);
    unsigned short* dst = hn + ((size_t)b * HW + p) * CCH + g * 16;
    *(uint4*)dst = u0;
    *(uint4*)(dst + 8) = u1;
  }
}

// ---------- MFMA GEMM, double-buffered pipeline (T3-minimal) --------------
// D[pos][ch] = sum_k Xt[b][pos][k] * W[ch][k] + bias
// Per k-step: issue global_load_lds for tile k+1 into buf^1, ds_read+MFMA on
// buf, then one __syncthreads (vmcnt(0)+barrier) -- staging latency hides
// under compute instead of being exposed per-step.
// PROJ=0: fused QKV: mat 0 -> pos-major bf16 * QSCALE (Q); mat 1 -> pos-major
//         (K); mat 2 -> ch-major (V).
// PROJ=1: fp32 ch-major out + residual.
template <int PROJ>
__global__ __launch_bounds__(256, 3) void mm_kernel(
    const unsigned short* __restrict__ Xt, const unsigned short* __restrict__ Wb,
    const float* __restrict__ b0, const float* __restrict__ b1,
    const float* __restrict__ b2, const float* __restrict__ resid,
    unsigned short* __restrict__ O0, unsigned short* __restrict__ O1,
    unsigned short* __restrict__ O2, float* __restrict__ Ofp) {
  int b = blockIdx.z;
  int p0 = blockIdx.x * 128;
  int c0g = blockIdx.y * 128;
  __shared__ __align__(16) unsigned short Xs[2][4096];  // 2 x 8KB
  __shared__ __align__(16) unsigned short Ws[2][4096];  // 2 x 8KB
  int t = threadIdx.x;
  int w = t >> 6, lane = t & 63, l15 = lane & 15, quad = lane >> 4;
  int wp = (w & 1) * 64, wc = (w >> 1) * 64;
  const unsigned short* Xb = Xt + (size_t)b * HW * CCH;
  const unsigned short* Wr = Wb + (size_t)c0g * CCH;
  f4 acc[4][4] = {};
  auto stage = [&](int k0, int bi) {
#pragma unroll
    for (int j = 0; j < 2; ++j) {
      int chk = w * 2 + j;             // 1KB chunk = 16 rows x 64B
      int r = chk * 16 + (lane >> 2);
      int c = (lane & 3) ^ (r & 3);    // XOR swizzle
      ldg_lds16(&Xb[(size_t)(p0 + r) * CCH + k0 + c * 8], &Xs[bi][chk * 512]);
      ldg_lds16(&Wr[(size_t)r * CCH + k0 + c * 8], &Ws[bi][chk * 512]);
    }
  };
  stage(0, 0);
  __syncthreads();  // vmcnt(0) drain + barrier: buf0 staged everywhere
  for (int k0 = 0, cur = 0; k0 < CCH; k0 += 32, cur ^= 1) {
    if (k0 + 32 < CCH) stage(k0 + 32, cur ^ 1);  // in flight during compute
    bfrag af[4], bf[4];
#pragma unroll
    for (int pt = 0; pt < 4; ++pt) {
      int r = wp + pt * 16 + l15;
      af[pt] = *(const bfrag*)&Xs[cur][r * 32 + (quad ^ (r & 3)) * 8];
    }
#pragma unroll
    for (int ct = 0; ct < 4; ++ct) {
      int r = wc + ct * 16 + l15;
      bf[ct] = *(const bfrag*)&Ws[cur][r * 32 + (quad ^ (r & 3)) * 8];
    }
#pragma unroll
    for (int pt = 0; pt < 4; ++pt)
#pragma unroll
      for (int ct = 0; ct < 4; ++ct)
        acc[pt][ct] = __builtin_amdgcn_mfma_f32_16x16x32_bf16(
            af[pt], bf[ct], acc[pt][ct], 0, 0, 0);
    __syncthreads();  // drains next-tile loads (vmcnt 0) + barrier
  }
  if (PROJ) {
#pragma unroll
    for (int ct = 0; ct < 4; ++ct) {
      int ch = c0g + wc + ct * 16 + l15;
      float bi = b0[ch];
#pragma unroll
      for (int pt = 0; pt < 4; ++pt) {
        int pos = p0 + wp + pt * 16 + quad * 4;
        f4 v = acc[pt][ct];
        size_t off = (size_t)b * CCH * HW + (size_t)ch * HW + pos;
        float4 rv = *(const float4*)&resid[off];
        float4 st;
        st.x = v.x + bi + rv.x; st.y = v.y + bi + rv.y;
        st.z = v.z + bi + rv.z; st.w = v.w + bi + rv.w;
        *(float4*)&Ofp[off] = st;
      }
    }
  } else {
    int mat = c0g >> 9;
    int c0 = c0g & 511;
    const float* bias = mat == 0 ? b0 : (mat == 1 ? b1 : b2);
    unsigned short* O = mat == 0 ? O0 : (mat == 1 ? O1 : O2);
    const float sc = (mat == 0) ? QSCALE : 1.0f;
#pragma unroll
    for (int ct = 0; ct < 4; ++ct) {
      int ch = c0 + wc + ct * 16 + l15;
      float bi = bias[ch];
#pragma unroll
      for (int pt = 0; pt < 4; ++pt) {
        int pos = p0 + wp + pt * 16 + quad * 4;
        f4 v = acc[pt][ct];
        if (mat < 2) {  // pos-major; lanes (l15) -> consecutive ch: 32B segs
          unsigned short* Op = O + (size_t)b * HW * CCH;
          Op[(size_t)(pos + 0) * CCH + ch] = f2bf((v.x + bi) * sc);
          Op[(size_t)(pos + 1) * CCH + ch] = f2bf((v.y + bi) * sc);
          Op[(size_t)(pos + 2) * CCH + ch] = f2bf((v.z + bi) * sc);
          Op[(size_t)(pos + 3) * CCH + ch] = f2bf((v.w + bi) * sc);
        } else {  // ch-major (V): quad-contiguous pos -> 64B segs
          unsigned short* Op = O + (size_t)b * CCH * HW;
          ushort4 st;
          st.x = f2bf(v.x + bi); st.y = f2bf(v.y + bi);
          st.z = f2bf(v.z + bi); st.w = f2bf(v.w + bi);
          *(ushort4*)&Op[(size_t)ch * HW + pos] = st;
        }
      }
    }
  }
}

// ---------- Flash attention: 256 thr / 128 q, dbuf K/V, 1 barrier per kt --
// r1 structure (best measured) + permlane32_swap P-exchange.
// Q pre-scaled by QSCALE (incl. log2e); fixed-base exp2 softmax.
// grid (64 bh, 8 qt) = 512 blocks -> 2 blocks/CU (64KB LDS each).
__global__ __launch_bounds__(256, 2) void attn_kernel(
    const unsigned short* __restrict__ Qt, const unsigned short* __restrict__ Kt,
    const unsigned short* __restrict__ Vc, unsigned short* __restrict__ Ot) {
  int bh = blockIdx.x;
  int b = bh >> 2, h = bh & 3;
  int q0 = blockIdx.y * 128;
  int t = threadIdx.x;
  int w = t >> 6, lane = t & 63;
  int l31 = lane & 31, half = lane >> 5;
  __shared__ __align__(16) unsigned short Ks[2][64 * 128];  // 2 x 16KB
  __shared__ __align__(16) unsigned short Vs[2][128 * 64];  // 2 x 16KB
  int q = q0 + w * 32 + l31;  // this lane's query
  const unsigned short* Kbase = Kt + (size_t)b * HW * CCH + h * HD;
  const unsigned short* Vbase = Vc + ((size_t)b * CCH + h * HD) * HW;
  // Q B-frags: B[k=ks*16+half*8+j][n=q], loop-invariant
  bfrag qf[8];
#pragma unroll
  for (int ks = 0; ks < 8; ++ks)
    qf[ks] = *(const bfrag*)&Qt[((size_t)b * HW + q) * CCH + h * HD +
                                ks * 16 + half * 8];
  f16v o[4] = {};   // PV accum: D[m=d (4x32)][n=q]
  float ls[4] = {}; // rotating partial row-sums (short dep chains)
  // staging: wave w owns chunks 4w..4w+3 of Ks and of Vs (1KB each)
  auto stage = [&](int kt, int bi) {
    int kk0 = kt * 64;
#pragma unroll
    for (int j = 0; j < 4; ++j) {
      int chk = w * 4 + j;
      {  // Ks chunk: 4 rows x 256B
        int r = chk * 4 + (lane >> 4);
        int c = (lane & 15) ^ (r & 15);
        ldg_lds16(&Kbase[(size_t)(kk0 + r) * CCH + c * 8], &Ks[bi][chk * 512]);
      }
      {  // Vs chunk: 8 rows x 128B
        int r = chk * 8 + (lane >> 3);
        int c = (lane & 7) ^ (r & 7);
        ldg_lds16(&Vbase[(size_t)r * HW + kk0 + c * 8], &Vs[bi][chk * 512]);
      }
    }
  };
  stage(0, 0);
  for (int kt = 0; kt < 16; ++kt) {
    __syncthreads();  // stage(kt) complete everywhere; prev-iter reads done
    if (kt < 15) stage(kt + 1, (kt + 1) & 1);  // overlaps compute below
    const unsigned short* K_ = Ks[kt & 1];
    const unsigned short* V_ = Vs[kt & 1];
    // QK^T: D[m=kk 2x32][n=q 32]; A = K rows from LDS, B = Q regs
    f16v S[2] = {};
    __builtin_amdgcn_s_setprio(1);
#pragma unroll
    for (int ks = 0; ks < 8; ++ks) {
      int c16 = ks * 2 + half;
#pragma unroll
      for (int mt = 0; mt < 2; ++mt) {
        int r = mt * 32 + l31;
        bfrag kf = *(const bfrag*)&K_[r * 128 + ((c16 ^ (r & 15)) << 3)];
        S[mt] = __builtin_amdgcn_mfma_f32_32x32x16_bf16(kf, qf[ks], S[mt],
                                                        0, 0, 0);
      }
    }
    __builtin_amdgcn_s_setprio(0);
    // exp2 softmax: p = 2^S (log2e folded into Q scale -> exact e^s softmax)
    unsigned pd[16];  // bf16 pairs, pd[mt*8+i] = C regs (2i,2i+1) of tile mt
#pragma unroll
    for (int mt = 0; mt < 2; ++mt)
#pragma unroll
      for (int i = 0; i < 8; ++i) {
        float p0 = EXP2(S[mt][2 * i]);
        float p1 = EXP2(S[mt][2 * i + 1]);
        ls[i & 3] += p0 + p1;
        pd[mt * 8 + i] = cvt_pk_bf16(p0, p1);
      }
    // P C-layout -> B-layout: one v_permlane32_swap per reg pair.
    // swap(a,c): a' = lane<32 ? own a : c[lane-32];
    //            c' = lane<32 ? a[lane+32] : own c.
#pragma unroll
    for (int mt = 0; mt < 2; ++mt)
#pragma unroll
      for (int s = 0; s < 2; ++s) {
        int base = mt * 8 + s * 4;
        unsigned a0 = pd[base + 0], a1 = pd[base + 1];
        unsigned c0 = pd[base + 2], c1 = pd[base + 3];
        asm("v_permlane32_swap_b32 %0, %1" : "+v"(a0), "+v"(c0));
        asm("v_permlane32_swap_b32 %0, %1" : "+v"(a1), "+v"(c1));
        union { unsigned u[4]; bfrag f; } pf;
        pf.u[0] = a0; pf.u[1] = a1; pf.u[2] = c0; pf.u[3] = c1;
        int c8 = (mt * 2 + s) * 2 + half;
        __builtin_amdgcn_s_setprio(1);
#pragma unroll
        for (int dt = 0; dt < 4; ++dt) {
          int r = dt * 32 + l31;
          bfrag vf = *(const bfrag*)&V_[r * 64 + ((c8 ^ (r & 7)) << 3)];
          o[dt] = __builtin_amdgcn_mfma_f32_32x32x16_bf16(vf, pf.f, o[dt],
                                                          0, 0, 0);
        }
        __builtin_amdgcn_s_setprio(0);
      }
  }
  // reduce l across the kk-halves (lane and lane^32 own complementary rows)
  float lrow = (ls[0] + ls[1]) + (ls[2] + ls[3]);
  lrow += __shfl_xor(lrow, 32);
  float inv = 1.f / lrow;
  unsigned short* Op = Ot + ((size_t)b * HW + q) * CCH + h * HD;
#pragma unroll
  for (int dt = 0; dt < 4; ++dt)
#pragma unroll
    for (int rg = 0; rg < 4; ++rg) {
      int d = dt * 32 + rg * 8 + half * 4;
      uint2 st;
      st.x = cvt_pk_bf16(o[dt][rg * 4 + 0] * inv, o[dt][rg * 4 + 1] * inv);
      st.y = cvt_pk_bf16(o[dt][rg * 4 + 2] * inv, o[dt][rg * 4 + 3] * inv);
      *(uint2*)&Op[d] = st;
    }
}

extern "C" void kernel_launch(void* const* d_in, const int* in_sizes, int n_in,
                              void* d_out, int out_size, void* d_ws,
                              size_t ws_size, hipStream_t stream) {
  const float* x = (const float*)d_in[0];
  const float* gamma = (const float*)d_in[1];
  const float* beta = (const float*)d_in[2];
  const float* wq = (const float*)d_in[3];
  const float* bq = (const float*)d_in[4];
  const float* wk = (const float*)d_in[5];
  const float* bk = (const float*)d_in[6];
  const float* wv = (const float*)d_in[7];
  const float* bv = (const float*)d_in[8];
  const float* wp = (const float*)d_in[9];
  const float* bp = (const float*)d_in[10];

  const size_t TS = (size_t)BATCH * HW * CCH;
  unsigned short* wB = (unsigned short*)d_ws;  // [4][512][512] bf16 (q,k,v,p)
  unsigned short* hn = wB + (size_t)4 * CCH * CCH;
  unsigned short* Qt = hn + TS;
  unsigned short* Kt = Qt + TS;
  unsigned short* Vc = Kt + TS;
  unsigned short* Ot = hn;  // reuse hn after QKV

  wcvt_kernel<<<dim3(256, 4), 256, 0, stream>>>(wq, wk, wv, wp, wB);
  gn_kernel<<<dim3(BATCH * 32), 256, 0, stream>>>(x, gamma, beta, hn);
  mm_kernel<0><<<dim3(8, 12, BATCH), 256, 0, stream>>>(
      hn, wB, bq, bk, bv, nullptr, Qt, Kt, Vc, nullptr);
  attn_kernel<<<dim3(64, 8), 256, 0, stream>>>(Qt, Kt, Vc, Ot);
  mm_kernel<1><<<dim3(8, 4, BATCH), 256, 0, stream>>>(
      Ot, wB + (size_t)3 * CCH * CCH, bp, bp, bp, x, nullptr, nullptr, nullptr,
      (float*)d_out);
}

// Round 5
// 206.323 us; speedup vs baseline: 1.1997x; 1.0247x over previous
//
#include <hip/hip_runtime.h>
#include <math.h>

#define CCH 512
#define NH 4
#define HD 128
#define HW 1024
#define BATCH 16
#define EPS 1e-5f

typedef __attribute__((ext_vector_type(8))) short bfrag;    // 8 bf16 = 4 VGPRs
typedef __attribute__((ext_vector_type(4))) float f4;
typedef __attribute__((ext_vector_type(16))) float f16v;    // 32x32 accum

static __device__ __forceinline__ unsigned short f2bf(float f) {
  union { float f; unsigned u; } v;
  v.f = f;
  unsigned r = v.u + 0x7fff + ((v.u >> 16) & 1);  // RNE
  return (unsigned short)(r >> 16);
}
// packed f32x2 -> bf16x2 in one VALU op (gfx950). src0 -> low half.
static __device__ __forceinline__ unsigned cvt_pk_bf16(float a, float b) {
  unsigned r;
  asm("v_cvt_pk_bf16_f32 %0, %1, %2" : "=v"(r) : "v"(a), "v"(b));
  return r;
}
// exp2 via HW transcendental (no log2e multiply; folded into Q scale)
#if defined(__has_builtin) && __has_builtin(__builtin_amdgcn_exp2f)
#define EXP2(x) __builtin_amdgcn_exp2f(x)
#else
#define EXP2(x) __expf((x) * 0.6931471805599453f)  // e^(x ln2) == 2^x
#endif
// async global->LDS, 16B/lane. LDS dest = wave-uniform base + lane*16.
static __device__ __forceinline__ void ldg_lds16(const unsigned short* g,
                                                 unsigned short* l) {
  __builtin_amdgcn_global_load_lds(
      (const __attribute__((address_space(1))) unsigned int*)g,
      (__attribute__((address_space(3))) unsigned int*)l, 16, 0, 0);
}

// softmax scale folded into Q GEMM epilogue. Includes log2(e) so the
// attention softmax can use raw v_exp_f32 (2^x): 2^(s*log2e) == e^s exactly.
#define QSCALE (0.08838834764831845f * 1.4426950408889634f)

// main-loop LDS swizzle: fold bits 0-3 of row into the 8-elem group select
// ((r^(r>>2))&3 instead of r&3: rows r,r+4 no longer alias -> 2-way banks)
#define SWZ(r) (((r) ^ ((r) >> 2)) & 3)

// ---------- weights fp32 -> bf16 (4 matrices stacked) ----------
__global__ __launch_bounds__(256) void wcvt_kernel(const float* __restrict__ s0,
                                                   const float* __restrict__ s1,
                                                   const float* __restrict__ s2,
                                                   const float* __restrict__ s3,
                                                   unsigned short* __restrict__ d) {
  const float* srcs[4] = {s0, s1, s2, s3};
  const float* s = srcs[blockIdx.y];
  unsigned short* dp = d + (size_t)blockIdx.y * CCH * CCH;
  int i = blockIdx.x * 256 + threadIdx.x;
  f4 v = ((const f4*)s)[i];
  ushort4 o;
  o.x = f2bf(v.x); o.y = f2bf(v.y); o.z = f2bf(v.z); o.w = f2bf(v.w);
  ((ushort4*)dp)[i] = o;
}

// ---------- GroupNorm -> position-major bf16 hn_t[b][hw][c] ----------
// Single global read: thread t holds channels 0..15 at positions 4t..4t+3 in
// registers (64 floats); stats via shuffle; write directly from registers.
__global__ __launch_bounds__(256) void gn_kernel(const float* __restrict__ x,
                                                 const float* __restrict__ gamma,
                                                 const float* __restrict__ beta,
                                                 unsigned short* __restrict__ hn) {
  int b = blockIdx.x >> 5, g = blockIdx.x & 31;
  const float* xp = x + ((size_t)b * CCH + g * 16) * HW;
  int t = threadIdx.x;
  float s = 0.f, ss = 0.f;
  const f4* xp4 = (const f4*)xp;
  f4 vv[16];
#pragma unroll
  for (int c = 0; c < 16; ++c) {
    f4 v = xp4[c * 256 + t];  // channel c, positions 4t..4t+3
    vv[c] = v;
    s += v.x + v.y + v.z + v.w;
    ss += v.x * v.x + v.y * v.y + v.z * v.z + v.w * v.w;
  }
#pragma unroll
  for (int off = 32; off > 0; off >>= 1) {
    s += __shfl_xor(s, off);
    ss += __shfl_xor(ss, off);
  }
  __shared__ float rs[4], rss[4];
  int w = t >> 6;
  if ((t & 63) == 0) { rs[w] = s; rss[w] = ss; }
  __syncthreads();
  s = rs[0] + rs[1] + rs[2] + rs[3];
  ss = rss[0] + rss[1] + rss[2] + rss[3];
  const float invn = 1.f / (16 * HW);
  float mean = s * invn;
  float var = ss * invn - mean * mean;
  float rstd = rsqrtf(var + EPS);
  float a_[16], b_[16];
#pragma unroll
  for (int c = 0; c < 16; ++c) {
    float gm = gamma[g * 16 + c] * rstd;
    a_[c] = gm;
    b_[c] = beta[g * 16 + c] - mean * gm;
  }
#pragma unroll
  for (int i = 0; i < 4; ++i) {
    int p = 4 * t + i;
    uint4 u0, u1;
    u0.x = cvt_pk_bf16(vv[0][i] * a_[0] + b_[0], vv[1][i] * a_[1] + b_[1]);
    u0.y = cvt_pk_bf16(vv[2][i] * a_[2] + b_[2], vv[3][i] * a_[3] + b_[3]);
    u0.z = cvt_pk_bf16(vv[4][i] * a_[4] + b_[4], vv[5][i] * a_[5] + b_[5]);
    u0.w = cvt_pk_bf16(vv[6][i] * a_[6] + b_[6], vv[7][i] * a_[7] + b_[7]);
    u1.x = cvt_pk_bf16(vv[8][i] * a_[8] + b_[8], vv[9][i] * a_[9] + b_[9]);
    u1.y = cvt_pk_bf16(vv[10][i] * a_[10] + b_[10], vv[11][i] * a_[11] + b_[11]);
    u1.z = cvt_pk_bf16(vv[12][i] * a_[12] + b_[12], vv[13][i] * a_[13] + b_[13]);
    u1.w = cvt_pk_bf16(vv[14][i] * a_[14] + b_[14], vv[15][i] * a_[15] + b_[15]);
    unsigned short* dst = hn + ((size_t)b * HW + p) * CCH + g * 16;
    *(uint4*)dst = u0;
    *(uint4*)(dst + 8) = u1;
  }
}

// ---------- MFMA GEMM, double-buffered pipeline ---------------------------
// D = Xt[b] @ W^T + bias over K=512, 128x128 block, 4 waves (64x64 each).
// MODE 0: Q,K (mats 0/1 of Wb): SWAPPED operands -> D[m=ch][n=pos], then
//         LDS-transpose epilogue -> pos-major bf16 rows (256B-contig stores,
//         full lines; Q scaled by QSCALE).
// MODE 1: V (Wb pre-offset): normal D[m=pos][n=ch] -> ch-major bf16.
// MODE 2: P (Wb pre-offset): normal -> fp32 ch-major + residual.
template <int MODE>
__global__ __launch_bounds__(256, 3) void mm_kernel(
    const unsigned short* __restrict__ Xt, const unsigned short* __restrict__ Wb,
    const float* __restrict__ b0, const float* __restrict__ b1,
    const float* __restrict__ resid,
    unsigned short* __restrict__ O0, unsigned short* __restrict__ O1,
    float* __restrict__ Ofp) {
  int b = blockIdx.z;
  int p0 = blockIdx.x * 128;
  int c0g = blockIdx.y * 128;
  __shared__ __align__(16) unsigned short LDS[16384];  // 32KB
#define XS(bi) (LDS + (bi) * 4096)
#define WS(bi) (LDS + 8192 + (bi) * 4096)
  int t = threadIdx.x;
  int w = t >> 6, lane = t & 63, l15 = lane & 15, quad = lane >> 4;
  int wp = (w & 1) * 64, wc = (w >> 1) * 64;
  const unsigned short* Xb = Xt + (size_t)b * HW * CCH;
  const unsigned short* Wr = Wb + (size_t)c0g * CCH;
  f4 acc[4][4] = {};
  auto stage = [&](int k0, int bi) {
#pragma unroll
    for (int j = 0; j < 2; ++j) {
      int chk = w * 2 + j;             // 1KB chunk = 16 rows x 64B
      int r = chk * 16 + (lane >> 2);
      int c = (lane & 3) ^ SWZ(r);     // XOR swizzle (bank-spread)
      ldg_lds16(&Xb[(size_t)(p0 + r) * CCH + k0 + c * 8], XS(bi) + chk * 512);
      ldg_lds16(&Wr[(size_t)r * CCH + k0 + c * 8], WS(bi) + chk * 512);
    }
  };
  stage(0, 0);
  __syncthreads();  // vmcnt(0) drain + barrier: buf0 staged everywhere
  for (int k0 = 0, cur = 0; k0 < CCH; k0 += 32, cur ^= 1) {
    if (k0 + 32 < CCH) stage(k0 + 32, cur ^ 1);  // in flight during compute
    bfrag af[4], bf[4];
#pragma unroll
    for (int pt = 0; pt < 4; ++pt) {
      int r = wp + pt * 16 + l15;
      af[pt] = *(const bfrag*)&XS(cur)[r * 32 + ((quad ^ SWZ(r)) << 3)];
    }
#pragma unroll
    for (int ct = 0; ct < 4; ++ct) {
      int r = wc + ct * 16 + l15;
      bf[ct] = *(const bfrag*)&WS(cur)[r * 32 + ((quad ^ SWZ(r)) << 3)];
    }
#pragma unroll
    for (int pt = 0; pt < 4; ++pt)
#pragma unroll
      for (int ct = 0; ct < 4; ++ct) {
        if (MODE == 0)  // swapped: D[m=ch][n=pos]
          acc[pt][ct] = __builtin_amdgcn_mfma_f32_16x16x32_bf16(
              bf[ct], af[pt], acc[pt][ct], 0, 0, 0);
        else
          acc[pt][ct] = __builtin_amdgcn_mfma_f32_16x16x32_bf16(
              af[pt], bf[ct], acc[pt][ct], 0, 0, 0);
      }
    __syncthreads();  // drains next-tile loads (vmcnt 0) + barrier
  }
  if (MODE == 0) {
    // acc[pt][ct]: ch = wc+ct*16+quad*4+i, pos = wp+pt*16+l15
    int mat = c0g >> 9;
    int c0 = c0g & 511;
    const float* bias = mat ? b1 : b0;
    unsigned short* O = mat ? O1 : O0;
    const float sc = mat ? 1.0f : QSCALE;
    // LDS transpose buffer: [pos 128][ch 128] bf16 = 32KB (reuses LDS).
    // 8B-granule XOR swizzle: granule g at row pos stored at g ^ ((pos&7)<<1)
#pragma unroll
    for (int ct = 0; ct < 4; ++ct) {
      f4 bi = *(const f4*)&bias[c0 + wc + ct * 16 + quad * 4];
      int g = (wc >> 2) + ct * 4 + quad;  // 8B granule index (0..31)
#pragma unroll
      for (int pt = 0; pt < 4; ++pt) {
        int pos = wp + pt * 16 + l15;
        f4 v = acc[pt][ct];
        uint2 d;
        d.x = cvt_pk_bf16((v.x + bi.x) * sc, (v.y + bi.y) * sc);
        d.y = cvt_pk_bf16((v.z + bi.z) * sc, (v.w + bi.w) * sc);
        int gs = g ^ ((pos & 7) << 1);
        *(uint2*)&LDS[pos * 128 + gs * 4] = d;
      }
    }
    __syncthreads();
    unsigned short* Op = O + (size_t)b * HW * CCH;
#pragma unroll
    for (int it = 0; it < 8; ++it) {
      int row = w * 32 + it * 4 + (lane >> 4);   // wave w owns rows w*32..+31
      int g0 = (2 * l15) ^ ((row & 7) << 1);     // 16B granule (even ^ even)
      uint4 val = *(const uint4*)&LDS[row * 128 + g0 * 4];
      *(uint4*)&Op[(size_t)(p0 + row) * CCH + c0 + l15 * 8] = val;
    }
  } else if (MODE == 1) {
    // normal: pos = p0+wp+pt*16+quad*4+i, ch = c0g+wc+ct*16+l15 (V ch-major)
#pragma unroll
    for (int ct = 0; ct < 4; ++ct) {
      int ch = c0g + wc + ct * 16 + l15;
      float bi = b0[ch];
      unsigned short* Op = O0 + (size_t)b * CCH * HW;
#pragma unroll
      for (int pt = 0; pt < 4; ++pt) {
        int pos = p0 + wp + pt * 16 + quad * 4;
        f4 v = acc[pt][ct];
        uint2 st;
        st.x = cvt_pk_bf16(v.x + bi, v.y + bi);
        st.y = cvt_pk_bf16(v.z + bi, v.w + bi);
        *(uint2*)&Op[(size_t)ch * HW + pos] = st;
      }
    }
  } else {
#pragma unroll
    for (int ct = 0; ct < 4; ++ct) {
      int ch = c0g + wc + ct * 16 + l15;
      float bi = b0[ch];
#pragma unroll
      for (int pt = 0; pt < 4; ++pt) {
        int pos = p0 + wp + pt * 16 + quad * 4;
        f4 v = acc[pt][ct];
        size_t off = (size_t)b * CCH * HW + (size_t)ch * HW + pos;
        float4 rv = *(const float4*)&resid[off];
        float4 st;
        st.x = v.x + bi + rv.x; st.y = v.y + bi + rv.y;
        st.z = v.z + bi + rv.z; st.w = v.w + bi + rv.w;
        *(float4*)&Ofp[off] = st;
      }
    }
  }
#undef XS
#undef WS
}

// ---------- Flash attention: 256 thr / 128 q, dbuf K/V, 1 barrier per kt --
// (frozen at round-4 best ~48us) permlane32_swap P-exchange, exp2 softmax.
__global__ __launch_bounds__(256, 2) void attn_kernel(
    const unsigned short* __restrict__ Qt, const unsigned short* __restrict__ Kt,
    const unsigned short* __restrict__ Vc, unsigned short* __restrict__ Ot) {
  int bh = blockIdx.x;
  int b = bh >> 2, h = bh & 3;
  int q0 = blockIdx.y * 128;
  int t = threadIdx.x;
  int w = t >> 6, lane = t & 63;
  int l31 = lane & 31, half = lane >> 5;
  __shared__ __align__(16) unsigned short Ks[2][64 * 128];  // 2 x 16KB
  __shared__ __align__(16) unsigned short Vs[2][128 * 64];  // 2 x 16KB
  int q = q0 + w * 32 + l31;  // this lane's query
  const unsigned short* Kbase = Kt + (size_t)b * HW * CCH + h * HD;
  const unsigned short* Vbase = Vc + ((size_t)b * CCH + h * HD) * HW;
  // Q B-frags: B[k=ks*16+half*8+j][n=q], loop-invariant
  bfrag qf[8];
#pragma unroll
  for (int ks = 0; ks < 8; ++ks)
    qf[ks] = *(const bfrag*)&Qt[((size_t)b * HW + q) * CCH + h * HD +
                                ks * 16 + half * 8];
  f16v o[4] = {};   // PV accum: D[m=d (4x32)][n=q]
  float ls[4] = {}; // rotating partial row-sums (short dep chains)
  // staging: wave w owns chunks 4w..4w+3 of Ks and of Vs (1KB each)
  auto stage = [&](int kt, int bi) {
    int kk0 = kt * 64;
#pragma unroll
    for (int j = 0; j < 4; ++j) {
      int chk = w * 4 + j;
      {  // Ks chunk: 4 rows x 256B
        int r = chk * 4 + (lane >> 4);
        int c = (lane & 15) ^ (r & 15);
        ldg_lds16(&Kbase[(size_t)(kk0 + r) * CCH + c * 8], &Ks[bi][chk * 512]);
      }
      {  // Vs chunk: 8 rows x 128B
        int r = chk * 8 + (lane >> 3);
        int c = (lane & 7) ^ (r & 7);
        ldg_lds16(&Vbase[(size_t)r * HW + kk0 + c * 8], &Vs[bi][chk * 512]);
      }
    }
  };
  stage(0, 0);
  for (int kt = 0; kt < 16; ++kt) {
    __syncthreads();  // stage(kt) complete everywhere; prev-iter reads done
    if (kt < 15) stage(kt + 1, (kt + 1) & 1);  // overlaps compute below
    const unsigned short* K_ = Ks[kt & 1];
    const unsigned short* V_ = Vs[kt & 1];
    // QK^T: D[m=kk 2x32][n=q 32]; A = K rows from LDS, B = Q regs
    f16v S[2] = {};
    __builtin_amdgcn_s_setprio(1);
#pragma unroll
    for (int ks = 0; ks < 8; ++ks) {
      int c16 = ks * 2 + half;
#pragma unroll
      for (int mt = 0; mt < 2; ++mt) {
        int r = mt * 32 + l31;
        bfrag kf = *(const bfrag*)&K_[r * 128 + ((c16 ^ (r & 15)) << 3)];
        S[mt] = __builtin_amdgcn_mfma_f32_32x32x16_bf16(kf, qf[ks], S[mt],
                                                        0, 0, 0);
      }
    }
    __builtin_amdgcn_s_setprio(0);
    // exp2 softmax: p = 2^S (log2e folded into Q scale -> exact e^s softmax)
    unsigned pd[16];  // bf16 pairs, pd[mt*8+i] = C regs (2i,2i+1) of tile mt
#pragma unroll
    for (int mt = 0; mt < 2; ++mt)
#pragma unroll
      for (int i = 0; i < 8; ++i) {
        float p0 = EXP2(S[mt][2 * i]);
        float p1 = EXP2(S[mt][2 * i + 1]);
        ls[i & 3] += p0 + p1;
        pd[mt * 8 + i] = cvt_pk_bf16(p0, p1);
      }
    // P C-layout -> B-layout: one v_permlane32_swap per reg pair.
#pragma unroll
    for (int mt = 0; mt < 2; ++mt)
#pragma unroll
      for (int s = 0; s < 2; ++s) {
        int base = mt * 8 + s * 4;
        unsigned a0 = pd[base + 0], a1 = pd[base + 1];
        unsigned c0 = pd[base + 2], c1 = pd[base + 3];
        asm("v_permlane32_swap_b32 %0, %1" : "+v"(a0), "+v"(c0));
        asm("v_permlane32_swap_b32 %0, %1" : "+v"(a1), "+v"(c1));
        union { unsigned u[4]; bfrag f; } pf;
        pf.u[0] = a0; pf.u[1] = a1; pf.u[2] = c0; pf.u[3] = c1;
        int c8 = (mt * 2 + s) * 2 + half;
        __builtin_amdgcn_s_setprio(1);
#pragma unroll
        for (int dt = 0; dt < 4; ++dt) {
          int r = dt * 32 + l31;
          bfrag vf = *(const bfrag*)&V_[r * 64 + ((c8 ^ (r & 7)) << 3)];
          o[dt] = __builtin_amdgcn_mfma_f32_32x32x16_bf16(vf, pf.f, o[dt],
                                                          0, 0, 0);
        }
        __builtin_amdgcn_s_setprio(0);
      }
  }
  // reduce l across the kk-halves (lane and lane^32 own complementary rows)
  float lrow = (ls[0] + ls[1]) + (ls[2] + ls[3]);
  lrow += __shfl_xor(lrow, 32);
  float inv = 1.f / lrow;
  unsigned short* Op = Ot + ((size_t)b * HW + q) * CCH + h * HD;
#pragma unroll
  for (int dt = 0; dt < 4; ++dt)
#pragma unroll
    for (int rg = 0; rg < 4; ++rg) {
      int d = dt * 32 + rg * 8 + half * 4;
      uint2 st;
      st.x = cvt_pk_bf16(o[dt][rg * 4 + 0] * inv, o[dt][rg * 4 + 1] * inv);
      st.y = cvt_pk_bf16(o[dt][rg * 4 + 2] * inv, o[dt][rg * 4 + 3] * inv);
      *(uint2*)&Op[d] = st;
    }
}

extern "C" void kernel_launch(void* const* d_in, const int* in_sizes, int n_in,
                              void* d_out, int out_size, void* d_ws,
                              size_t ws_size, hipStream_t stream) {
  const float* x = (const float*)d_in[0];
  const float* gamma = (const float*)d_in[1];
  const float* beta = (const float*)d_in[2];
  const float* wq = (const float*)d_in[3];
  const float* bq = (const float*)d_in[4];
  const float* wk = (const float*)d_in[5];
  const float* bk = (const float*)d_in[6];
  const float* wv = (const float*)d_in[7];
  const float* bv = (const float*)d_in[8];
  const float* wp = (const float*)d_in[9];
  const float* bp = (const float*)d_in[10];

  const size_t TS = (size_t)BATCH * HW * CCH;
  unsigned short* wB = (unsigned short*)d_ws;  // [4][512][512] bf16 (q,k,v,p)
  unsigned short* hn = wB + (size_t)4 * CCH * CCH;
  unsigned short* Qt = hn + TS;
  unsigned short* Kt = Qt + TS;
  unsigned short* Vc = Kt + TS;
  unsigned short* Ot = hn;  // reuse hn after QKV

  wcvt_kernel<<<dim3(256, 4), 256, 0, stream>>>(wq, wk, wv, wp, wB);
  gn_kernel<<<dim3(BATCH * 32), 256, 0, stream>>>(x, gamma, beta, hn);
  // Q,K (swapped-operand path; mats 0/1 of wB)
  mm_kernel<0><<<dim3(8, 8, BATCH), 256, 0, stream>>>(
      hn, wB, bq, bk, nullptr, Qt, Kt, nullptr);
  // V (normal path; wB pre-offset to wv)
  mm_kernel<1><<<dim3(8, 4, BATCH), 256, 0, stream>>>(
      hn, wB + (size_t)2 * CCH * CCH, bv, nullptr, nullptr, Vc, nullptr,
      nullptr);
  attn_kernel<<<dim3(64, 8), 256, 0, stream>>>(Qt, Kt, Vc, Ot);
  // P-projection + residual (wB pre-offset to wp)
  mm_kernel<2><<<dim3(8, 4, BATCH), 256, 0, stream>>>(
      Ot, wB + (size_t)3 * CCH * CCH, bp, nullptr, x, nullptr, nullptr,
      (float*)d_out);
}